// Round 7
// baseline (1444.966 us; speedup 1.0000x reference)
//
#include <hip/hip_runtime.h>

#define B 128
#define T 1500
#define NI 80        // N_MELS
#define H 128        // HIDDEN
#define G 384        // 3*H
#define TT 64        // t-tile for gx gemm

typedef float v2f __attribute__((ext_vector_type(2)));

__device__ __forceinline__ float sigf(float x) { return 1.0f / (1.0f + __expf(-x)); }
__device__ __forceinline__ float tanhfast(float x) { return 1.0f - 2.0f / (1.0f + __expf(2.0f * x)); }
__device__ __forceinline__ v2f pkfma(v2f a, v2f b, v2f c) { return __builtin_elementwise_fma(a, b, c); }

// butterfly add lane^1 via DPP quad_perm [1,0,3,2] (VALU pipe)
__device__ __forceinline__ float qsum1(float v) {
    int a = __builtin_bit_cast(int, v);
    int c = __builtin_amdgcn_update_dpp(0, a, 0xB1, 0xF, 0xF, true);
    return v + __builtin_bit_cast(float, c);
}

// ---------------- gx GEMM (round-4 version, known-good ~285us) ----------------
__global__ __launch_bounds__(384)
void gx_gemm_kernel(const float* __restrict__ x, const float* __restrict__ w_ih,
                    const float* __restrict__ b_ih, float* __restrict__ gx,
                    int t0, int ct) {
    int tile = blockIdx.x;
    int b = blockIdx.y;
    int tl0 = tile * TT;
    if (tl0 >= ct) return;
    int n = (ct - tl0 < TT) ? (ct - tl0) : TT;
    int tid = threadIdx.x;  // = output g

    __shared__ __align__(16) float xs[TT * NI];   // 20 KB
    const float4* xsrc4 = (const float4*)(x + ((size_t)b * T + (size_t)(t0 + tl0)) * NI);
    int total4 = n * (NI / 4);
    for (int i = tid; i < total4; i += 384) ((float4*)xs)[i] = xsrc4[i];

    v2f w2[40];
    const v2f* wr = (const v2f*)(w_ih + (size_t)tid * NI);
#pragma unroll
    for (int i = 0; i < 40; ++i) w2[i] = wr[i];
    float bias = b_ih[tid];
    __syncthreads();

    float* gout = gx + ((size_t)b * ct + (size_t)tl0) * G + tid;
    int tt = 0;
    for (; tt + 2 <= n; tt += 2) {
        const float4* xa4 = (const float4*)(xs + tt * NI);
        const float4* xb4 = (const float4*)(xs + (tt + 1) * NI);
        v2f a0 = {0.f, 0.f}, a1 = {0.f, 0.f}, c0 = {0.f, 0.f}, c1 = {0.f, 0.f};
#pragma unroll
        for (int i = 0; i < 20; ++i) {
            float4 xa = xa4[i];
            float4 xb = xb4[i];
            v2f alo = {xa.x, xa.y}, ahi = {xa.z, xa.w};
            v2f blo = {xb.x, xb.y}, bhi = {xb.z, xb.w};
            a0 = pkfma(w2[2 * i], alo, a0);
            a1 = pkfma(w2[2 * i + 1], ahi, a1);
            c0 = pkfma(w2[2 * i], blo, c0);
            c1 = pkfma(w2[2 * i + 1], bhi, c1);
        }
        gout[(size_t)tt * G]       = bias + ((a0.x + a0.y) + (a1.x + a1.y));
        gout[(size_t)(tt + 1) * G] = bias + ((c0.x + c0.y) + (c1.x + c1.y));
    }
    if (tt < n) {
        const float4* xa4 = (const float4*)(xs + tt * NI);
        v2f a0 = {0.f, 0.f}, a1 = {0.f, 0.f};
#pragma unroll
        for (int i = 0; i < 20; ++i) {
            float4 xa = xa4[i];
            v2f alo = {xa.x, xa.y}, ahi = {xa.z, xa.w};
            a0 = pkfma(w2[2 * i], alo, a0);
            a1 = pkfma(w2[2 * i + 1], ahi, a1);
        }
        gout[(size_t)tt * G] = bias + ((a0.x + a0.y) + (a1.x + a1.y));
    }
}

// ---------------- scan: 2 batches per block ----------------
// 512 threads: half = tid>>8 selects batch (waves 0-3 vs 4-7 -> each SIMD hosts one
// wave of EACH batch: independent dep chains cover each other's stalls).
// Within a half: local = tid&255, j = local>>1, q = local&1; thread holds W_hh rows
// {j, j+H, j+2H} k-slice [64q,64q+64) (48 float4 regs). Per step: 16 ds_read_b128 (h),
// 96 pk_fma (6 independent acc chains), xor1 DPP reduce, gates (all lanes, redundant),
// h write. gx via distance-2 register prefetch. Raw s_barrier + lgkmcnt-only wait.
__global__ __launch_bounds__(512, 2)
void scan_kernel(const float* __restrict__ gx, const float* __restrict__ w_hh,
                 const float* __restrict__ b_hh, float* __restrict__ h_state,
                 int ct, int first, int last,
                 const float* __restrict__ x,
                 const float* __restrict__ w_ih_b, const float* __restrict__ b_ih_b,
                 const float* __restrict__ b_hh_b,
                 const float* __restrict__ w1, const float* __restrict__ b1,
                 const float* __restrict__ w2, const float* __restrict__ b2,
                 float* __restrict__ out) {
    int tid = threadIdx.x;
    int half = tid >> 8;
    int b = blockIdx.x * 2 + half;
    int local = tid & 255;
    int j = local >> 1;
    int q = local & 1;
    int jpad = j + ((j >> 6) << 2);   // +4-float pad between the two 64-float q-slices

    __shared__ __align__(16) float hs[2][2][132];
    __shared__ __align__(16) float tail_gx[2][G];
    __shared__ __align__(16) float last_s[2][2 * H];
    __shared__ __align__(16) float xb_s[2][NI];

    // W_hh fragments: rows {j, j+H, j+2H}, k in [64q, 64q+64)
    float4 WR4[16], WZ4[16], WN4[16];
    {
        const float4* wp = (const float4*)w_hh;
        size_t base = (size_t)j * 32 + 16 * q;
#pragma unroll
        for (int i = 0; i < 16; ++i) {
            WR4[i] = wp[base + i];
            WZ4[i] = wp[base + (size_t)H * 32 + i];
            WN4[i] = wp[base + (size_t)2 * H * 32 + i];
        }
    }
    float br = b_hh[j], bz = b_hh[j + H], bn = b_hh[j + 2 * H];

    float h_cur = 0.f;
    if (!first) h_cur = h_state[b * H + j];
    if (q == 0) hs[half][0][jpad] = h_cur;

    // gx prefetch registers, distance 2 (set A even steps, set B odd steps)
    float ga0, ga1, ga2, gb0 = 0.f, gb1 = 0.f, gb2 = 0.f;
    {
        const float* gp = gx + (size_t)b * ct * G;
        ga0 = gp[j]; ga1 = gp[j + H]; ga2 = gp[j + 2 * H];
        if (ct > 1) { gb0 = gp[G + j]; gb1 = gp[G + j + H]; gb2 = gp[G + j + 2 * H]; }
    }
    __syncthreads();   // prologue only

    auto step = [&](int TL, int SB, float& g0, float& g1, float& g2) {
        const float4* hv4 = (const float4*)(&hs[half][SB][0] + 68 * q);
        v2f arL = {0.f, 0.f}, arH = {0.f, 0.f};
        v2f azL = {0.f, 0.f}, azH = {0.f, 0.f};
        v2f anL = {0.f, 0.f}, anH = {0.f, 0.f};
#pragma unroll
        for (int i = 0; i < 16; ++i) {
            float4 hv = hv4[i];
            v2f hlo = {hv.x, hv.y}, hhi = {hv.z, hv.w};
            arL = pkfma(v2f{WR4[i].x, WR4[i].y}, hlo, arL);
            azL = pkfma(v2f{WZ4[i].x, WZ4[i].y}, hlo, azL);
            anL = pkfma(v2f{WN4[i].x, WN4[i].y}, hlo, anL);
            arH = pkfma(v2f{WR4[i].z, WR4[i].w}, hhi, arH);
            azH = pkfma(v2f{WZ4[i].z, WZ4[i].w}, hhi, azH);
            anH = pkfma(v2f{WN4[i].z, WN4[i].w}, hhi, anH);
        }
        float ar = (arL.x + arL.y) + (arH.x + arH.y);
        float az = (azL.x + azL.y) + (azH.x + azH.y);
        float an = (anL.x + anL.y) + (anH.x + anH.y);
        ar = qsum1(ar); az = qsum1(az); an = qsum1(an);
        float r = sigf(g0 + br + ar);
        float z = sigf(g1 + bz + az);
        float n = tanhfast(g2 + r * (bn + an));
        h_cur = (1.f - z) * n + z * h_cur;
        if (q == 0) hs[half][SB ^ 1][jpad] = h_cur;
        if (TL + 2 < ct) {
            const float* gp = gx + ((size_t)b * ct + TL + 2) * G;
            g0 = gp[j]; g1 = gp[j + H]; g2 = gp[j + 2 * H];
        }
        asm volatile("s_waitcnt lgkmcnt(0)\n\ts_barrier" ::: "memory");
    };

    int tl = 0;
    for (; tl + 1 < ct; tl += 2) {
        step(tl,     0, ga0, ga1, ga2);
        step(tl + 1, 1, gb0, gb1, gb2);
    }
    if (tl < ct) step(tl, 0, ga0, ga1, ga2);

    if (!last) {
        if (q == 0) h_state[b * H + j] = h_cur;
        return;
    }

    // ---- backward single step (h0 = 0) + MLP head, per half ----
    if (local < NI) xb_s[half][local] = x[((size_t)b * T + (T - 1)) * NI + local];
    if (q == 0) last_s[half][j] = h_cur;  // forward final hidden
    __syncthreads();

    for (int gg = local; gg < G; gg += 256) {
        const float4* wbr = (const float4*)(w_ih_b + (size_t)gg * NI);
        const float4* xv = (const float4*)xb_s[half];
        float a0 = 0.f, a1 = 0.f, a2 = 0.f, a3 = 0.f;
#pragma unroll
        for (int i = 0; i < 20; ++i) {
            float4 wv = wbr[i]; float4 x4 = xv[i];
            a0 = fmaf(wv.x, x4.x, a0); a1 = fmaf(wv.y, x4.y, a1);
            a2 = fmaf(wv.z, x4.z, a2); a3 = fmaf(wv.w, x4.w, a3);
        }
        tail_gx[half][gg] = b_ih_b[gg] + ((a0 + a1) + (a2 + a3));
    }
    __syncthreads();

    if (local < H) {
        float r = sigf(tail_gx[half][local] + b_hh_b[local]);
        float z = sigf(tail_gx[half][local + H] + b_hh_b[local + H]);
        float n = tanhfast(tail_gx[half][local + 2 * H] + r * b_hh_b[local + 2 * H]);
        last_s[half][H + local] = (1.f - z) * n;  // + z*0
    }
    __syncthreads();

    if (local < 64) {
        const float4* w1r = (const float4*)(w1 + (size_t)local * 2 * H);
        const float4* lv = (const float4*)last_s[half];
        float a0 = 0.f, a1 = 0.f, a2 = 0.f, a3 = 0.f;
#pragma unroll
        for (int i = 0; i < 64; ++i) {
            float4 wv = w1r[i]; float4 l4 = lv[i];
            a0 = fmaf(wv.x, l4.x, a0); a1 = fmaf(wv.y, l4.y, a1);
            a2 = fmaf(wv.z, l4.z, a2); a3 = fmaf(wv.w, l4.w, a3);
        }
        float v = b1[local] + ((a0 + a1) + (a2 + a3));
        v = fmaxf(v, 0.f) * w2[local];
#pragma unroll
        for (int off = 32; off > 0; off >>= 1) v += __shfl_down(v, off);
        if (local == 0) out[b] = v + b2[0];
    }
}

extern "C" void kernel_launch(void* const* d_in, const int* in_sizes, int n_in,
                              void* d_out, int out_size, void* d_ws, size_t ws_size,
                              hipStream_t stream) {
    (void)in_sizes; (void)n_in; (void)out_size;
    const float* x      = (const float*)d_in[0];
    const float* w_ih_f = (const float*)d_in[1];
    const float* w_hh_f = (const float*)d_in[2];
    const float* b_ih_f = (const float*)d_in[3];
    const float* b_hh_f = (const float*)d_in[4];
    const float* w_ih_b = (const float*)d_in[5];
    const float* w_hh_b = (const float*)d_in[6];  // unused: h0=0 makes gh_b = b_hh_b
    const float* b_ih_b = (const float*)d_in[7];
    const float* b_hh_b = (const float*)d_in[8];
    const float* w1     = (const float*)d_in[9];
    const float* b1     = (const float*)d_in[10];
    const float* w2     = (const float*)d_in[11];
    const float* b2     = (const float*)d_in[12];
    (void)w_hh_b;
    float* out = (float*)d_out;

    float* h_state = (float*)d_ws;                 // B*H floats
    float* gxbuf = h_state + B * H;
    size_t hbytes = (size_t)B * H * sizeof(float);
    size_t avail = ws_size > hbytes ? ws_size - hbytes : 0;
    long long chunkT = (long long)(avail / ((size_t)B * G * sizeof(float)));
    if (chunkT > T) chunkT = T;
    if (chunkT < 1) chunkT = 1;

    for (int t0 = 0; t0 < T; t0 += (int)chunkT) {
        int ct = (T - t0 < (int)chunkT) ? (T - t0) : (int)chunkT;
        int ntiles = (ct + TT - 1) / TT;
        gx_gemm_kernel<<<dim3(ntiles, B), dim3(384), 0, stream>>>(
            x, w_ih_f, b_ih_f, gxbuf, t0, ct);
        scan_kernel<<<dim3(B / 2), dim3(512), 0, stream>>>(
            gxbuf, w_hh_f, b_hh_f, h_state, ct,
            (t0 == 0) ? 1 : 0, (t0 + ct >= T) ? 1 : 0,
            x, w_ih_b, b_ih_b, b_hh_b, w1, b1, w2, b2, out);
    }
}